// Round 11
// baseline (247.599 us; speedup 1.0000x reference)
//
#include <hip/hip_runtime.h>
#include <hip/hip_cooperative_groups.h>
#include <stdint.h>

namespace cg = cooperative_groups;

#define NSEL 300
#define BB 2
#define QQ 900
#define CC 91
#define NQC (QQ * CC)   // 81900
#define MH 128
#define MW 128
#define TGT 512

#define NBUCKET 4096
#define CAND_CAP 4096
#define NCHUNK 16                 // chunks per batch
#define CHUNK 5119                // ceil(81900/16)

typedef float floatx4 __attribute__((ext_vector_type(4)));

// ---- d_ws byte offsets (proven-safe <=1.25MB footprint) ----
#define WS_CAND   0               // u64 [2][4096]   (65536 B)
#define WS_KEYS   65536           // u32 [2][81900]  (655200 B)
#define WS_PART   720896          // u32 [32][4096]  (524288 B)
#define WS_SEL    1245184         // int [600]
#define WS_CUT    1247584         // u32 [2]
#define WS_COUNT  1247592         // int [2]

// ------- Cooperative top-k: keys+hist | scan->cut | collect | rank -------
__global__ __launch_bounds__(256) void topk_coop_kernel(
    const float* __restrict__ logits,    // [B,Q,C]
    const float* __restrict__ boxes_in,  // [B,Q,4]
    const float* __restrict__ logvars,   // [B,Q,4]
    const int*   __restrict__ tsizes,    // [B,2]
    float* __restrict__ out,
    uint8_t* __restrict__ ws)
{
    __shared__ unsigned long long scand[CAND_CAP];   // 32KB; aliased as hist
    uint32_t* hist = (uint32_t*)scand;               // first 16KB in phase 1
    __shared__ uint32_t wsum[4];

    cg::grid_group grid = cg::this_grid();

    const int blk   = blockIdx.x;          // 0..31
    const int b     = blk >> 4;
    const int chunk = blk & 15;
    const int tid   = threadIdx.x;
    const int lane  = tid & 63;
    const int wid   = tid >> 6;

    uint32_t* keys_all = (uint32_t*)(ws + WS_KEYS);
    uint32_t* part_all = (uint32_t*)(ws + WS_PART);
    uint32_t* cutp     = (uint32_t*)(ws + WS_CUT);
    int*      countp   = (int*)(ws + WS_COUNT);
    unsigned long long* cand_all = (unsigned long long*)(ws + WS_CAND);

    // ---------- Phase 1: keys + per-block histogram ----------
    {
        uint32_t* keys = keys_all + (size_t)b * NQC;
        uint32_t* part = part_all + (size_t)blk * NBUCKET;

        for (int i = tid; i < NBUCKET; i += 256) hist[i] = 0u;
        __syncthreads();

        const int base = chunk * CHUNK;
        int end = base + CHUNK; if (end > NQC) end = NQC;
        const float* lg = logits + (size_t)b * NQC;

        for (int i = base + tid; i < end; i += 256) {
            float x = lg[i];
            float p = 1.0f / (1.0f + expf(-x));      // identical expression
            uint32_t key = __float_as_uint(p);
            keys[i] = key;
            atomicAdd(&hist[key >> 18], 1u);
        }
        __syncthreads();

        for (int i = tid; i < NBUCKET; i += 256) part[i] = hist[i];
    }
    grid.sync();

    // ---------- Phase 2: reduce partials + suffix scan -> cut (blocks 0,1) --
    if (blk < 2) {
        const int b2 = blk;
        const uint32_t* part = part_all + (size_t)b2 * NCHUNK * NBUCKET;

        // thread owns buckets 16t..16t+15
        uint32_t h[16];
        #pragma unroll
        for (int j = 0; j < 16; ++j) h[j] = 0u;
        #pragma unroll
        for (int p = 0; p < NCHUNK; ++p) {
            const uint32_t* pp = part + (size_t)p * NBUCKET + 16 * tid;
            #pragma unroll
            for (int w = 0; w < 4; ++w) {
                uint4 v = *(const uint4*)(pp + 4 * w);
                h[4*w+0] += v.x; h[4*w+1] += v.y; h[4*w+2] += v.z; h[4*w+3] += v.w;
            }
        }
        uint32_t val = 0;
        #pragma unroll
        for (int j = 0; j < 16; ++j) val += h[j];

        // wave suffix scan over 256 threads (4 waves)
        uint32_t acc = val;
        #pragma unroll
        for (int off = 1; off < 64; off <<= 1) {
            uint32_t o = __shfl_down(acc, off, 64);
            if (lane + off < 64) acc += o;
        }
        if (lane == 0) wsum[wid] = acc;
        __syncthreads();
        uint32_t later = 0;
        for (int w = wid + 1; w < 4; ++w) later += wsum[w];
        const uint32_t sfx      = acc + later;
        const uint32_t sfx_next = sfx - val;

        if (sfx >= NSEL && sfx_next < NSEL) {
            int a = (int)sfx_next;
            int cut = 16 * tid;
            for (int k = 15; k >= 0; --k) {
                a += (int)h[k];
                if (a >= NSEL) { cut = 16 * tid + k; break; }
            }
            cutp[b2]   = (uint32_t)cut;
            countp[b2] = 0;
        }
    }
    grid.sync();

    // ---------- Phase 3: parallel collect (all 32 blocks, L2-hot keys) -----
    {
        const uint32_t cut = cutp[b];
        const uint32_t* keys = keys_all + (size_t)b * NQC;
        unsigned long long* cand = cand_all + (size_t)b * CAND_CAP;

        const int base = chunk * CHUNK;
        int end = base + CHUNK; if (end > NQC) end = NQC;

        for (int i = base + tid; i < end; i += 256) {
            uint32_t key = keys[i];
            if ((key >> 18) >= cut) {
                int pos = atomicAdd(&countp[b], 1);
                if (pos < CAND_CAP) {
                    cand[pos] = ((unsigned long long)key << 32)
                              | (uint32_t)(~(uint32_t)i);
                }
            }
        }
    }
    grid.sync();

    // ---------- Phase 4: rank-select + epilogue (blocks 0,1) ----------
    if (blk < 2) {
        const int b2 = blk;
        int count = countp[b2];
        if (count > CAND_CAP) count = CAND_CAP;

        const unsigned long long* gcand = cand_all + (size_t)b2 * CAND_CAP;
        for (int i = tid; i < count; i += 256) scand[i] = gcand[i];
        __syncthreads();

        float* out_scores = out;                 // [B*NSEL]
        float* out_labels = out + 600;
        float* out_boxes  = out + 1200;
        float* out_unc    = out + 3600;
        int*   sel        = (int*)(ws + WS_SEL);

        for (int i = tid; i < count; i += 256) {
            const unsigned long long my = scand[i];
            int r = 0;
            for (int j = 0; j < count; ++j) r += (scand[j] > my) ? 1 : 0;
            if (r < NSEL) {
                const uint32_t key = (uint32_t)(my >> 32);
                const uint32_t idx = ~((uint32_t)(my & 0xFFFFFFFFull));
                const int q = (int)(idx / CC);
                const int label = (int)(idx - (uint32_t)q * CC);
                const int o = b2 * NSEL + r;

                out_scores[o] = __uint_as_float(key);
                out_labels[o] = (float)label;

                const float* bx = boxes_in + ((size_t)(b2 * QQ + q)) * 4;
                float cx = bx[0], cy = bx[1], w = bx[2], hgt = bx[3];
                float hh2 = (float)tsizes[b2 * 2 + 0];
                float ww2 = (float)tsizes[b2 * 2 + 1];
                out_boxes[o * 4 + 0] = (cx - 0.5f * w) * ww2;
                out_boxes[o * 4 + 1] = (cy - 0.5f * hgt) * hh2;
                out_boxes[o * 4 + 2] = (cx + 0.5f * w) * ww2;
                out_boxes[o * 4 + 3] = (cy + 0.5f * hgt) * hh2;

                const float* gv = logvars + ((size_t)(b2 * QQ + q)) * 4;
                float s0 = gv[0] + gv[1];
                float s1 = s0 + gv[2];
                float s2 = s1 + gv[3];
                out_unc[o] = s2 * 0.25f;

                sel[o] = q;
            }
        }
    }
}

// ---------------- K3: bilinear upsample 128->512 + threshold ----------
// Byte-identical to R10 (register-cached blends + burst nt-stores).
__global__ __launch_bounds__(256) void mask_kernel(
    const float* __restrict__ masks_in,  // [B,Q,128,128]
    const int*   __restrict__ sel,       // [B*NSEL]
    float* __restrict__ out_masks)       // [B*NSEL,512,512]
{
    __shared__ float S[18 * MW];         // 9216 B

    const int xg = threadIdx.x & 127;    // output cols 4xg..4xg+3
    const int rh = threadIdx.x >> 7;     // row half (0/1) within 64-row item
    const int cm1 = (xg == 0)   ? 0   : xg - 1;
    const int cp1 = (xg == 127) ? 127 : xg + 1;
    const bool eL = (xg == 0);
    const bool eR = (xg == 127);

    const int it0 = 3 * blockIdx.x;      // exactly 3 items per block
    for (int item = it0; item < it0 + 3; ++item) {
        const int m = item >> 3;         // 0..599
        const int e = item & 7;          // eighth: 64 rows
        const int b = m / NSEL;
        const int q = sel[m];

        const float* src = masks_in + ((size_t)(b * QQ + q)) * (MH * MW);
        float* dst = out_masks + (size_t)m * (TGT * TGT);

        const int y0   = e * 64;
        const int r_lo = (e == 0) ? 0   : (16 * e - 1);
        const int r_hi = (e == 7) ? 127 : (16 * e + 16);
        const int nrows = r_hi - r_lo + 1;   // 17 or 18

        {
            const float4* s4 = (const float4*)(src + (size_t)r_lo * MW);
            float4* d4 = (float4*)S;
            const int n4 = nrows * (MW / 4);
            for (int i = threadIdx.x; i < n4; i += 256) d4[i] = s4[i];
        }
        __syncthreads();

        // ---- Phase 1: horizontal blends for input rows k0-1 .. k0+8 ----
        const int k0    = 16 * e + 8 * rh;   // first out-row group index
        const int rbase = k0 - 1;
        floatx4 h[10];
        #pragma unroll
        for (int j = 0; j < 10; ++j) {
            int r = rbase + j;
            r = (r < 0) ? 0 : (r > MH - 1 ? MH - 1 : r);
            const float* R = S + (r - r_lo) * MW;
            const float a = R[cm1];
            const float c = R[xg];
            const float p = R[cp1];
            floatx4 v;
            v.x = eL ? c : fmaf(0.375f, a, 0.625f * c);
            v.y = eL ? c : fmaf(0.125f, a, 0.875f * c);
            v.z = eR ? c : fmaf(0.125f, p, 0.875f * c);
            v.w = eR ? c : fmaf(0.375f, p, 0.625f * c);
            h[j] = v;
        }

        // ---- Phase 2: vertical lerps + burst stores ----
        float* dhalf = dst + (size_t)(y0 + rh * 32) * TGT + 4 * xg;
        #pragma unroll
        for (int g = 0; g < 8; ++g) {
            const floatx4 hA = h[g];
            const floatx4 hB = h[g + 1];
            const floatx4 hC = h[g + 2];
            const floatx4 dAB = hB - hA;
            const floatx4 dBC = hC - hB;

            floatx4 vA, vB, vC, vD;
            #pragma unroll
            for (int u = 0; u < 4; ++u) {
                vA[u] = fmaf(0.625f, dAB[u], hA[u]);
                vB[u] = fmaf(0.875f, dAB[u], hA[u]);
                vC[u] = fmaf(0.125f, dBC[u], hB[u]);
                vD[u] = fmaf(0.375f, dBC[u], hB[u]);
            }
            floatx4 rA, rB, rC, rD;
            #pragma unroll
            for (int u = 0; u < 4; ++u) {
                rA[u] = (vA[u] > 0.0f) ? 1.0f : 0.0f;
                rB[u] = (vB[u] > 0.0f) ? 1.0f : 0.0f;
                rC[u] = (vC[u] > 0.0f) ? 1.0f : 0.0f;
                rD[u] = (vD[u] > 0.0f) ? 1.0f : 0.0f;
            }
            floatx4* p0 = (floatx4*)(dhalf + (size_t)(4 * g    ) * TGT);
            floatx4* p1 = (floatx4*)(dhalf + (size_t)(4 * g + 1) * TGT);
            floatx4* p2 = (floatx4*)(dhalf + (size_t)(4 * g + 2) * TGT);
            floatx4* p3 = (floatx4*)(dhalf + (size_t)(4 * g + 3) * TGT);
            __builtin_nontemporal_store(rA, p0);
            __builtin_nontemporal_store(rB, p1);
            __builtin_nontemporal_store(rC, p2);
            __builtin_nontemporal_store(rD, p3);
        }
        __syncthreads();   // LDS reuse guard before next item's stage
    }
}

extern "C" void kernel_launch(void* const* d_in, const int* in_sizes, int n_in,
                              void* d_out, int out_size, void* d_ws, size_t ws_size,
                              hipStream_t stream) {
    (void)in_sizes; (void)n_in; (void)out_size; (void)ws_size;

    const float* pred_logits  = (const float*)d_in[0];  // [2,900,91]
    const float* pred_boxes   = (const float*)d_in[1];  // [2,900,4]
    const float* pred_masks   = (const float*)d_in[2];  // [2,900,128,128]
    const float* pred_logvars = (const float*)d_in[3];  // [2,900,4]
    const int*   target_sizes = (const int*)d_in[4];    // [2,2]

    float*   out = (float*)d_out;
    uint8_t* ws  = (uint8_t*)d_ws;

    void* args[6] = {
        (void*)&pred_logits, (void*)&pred_boxes, (void*)&pred_logvars,
        (void*)&target_sizes, (void*)&out, (void*)&ws
    };
    hipLaunchCooperativeKernel((const void*)topk_coop_kernel,
                               dim3(32), dim3(256), args, 0, stream);

    float* out_masks = out + 4200;
    const int* sel = (const int*)(ws + WS_SEL);
    hipLaunchKernelGGL(mask_kernel, dim3(1600), dim3(256), 0, stream,
                       pred_masks, sel, out_masks);
}

// Round 12
// 223.529 us; speedup vs baseline: 1.1077x; 1.1077x over previous
//
#include <hip/hip_runtime.h>
#include <stdint.h>

#define NSEL 300
#define BB 2
#define QQ 900
#define CC 91
#define NQC (QQ * CC)   // 81900
#define MH 128
#define MW 128
#define TGT 512

#define NBUCKET 4096
#define CAND_CAP 4096
#define NCHUNK 16                 // chunks per batch
#define CHUNK 5119                // ceil(81900/16)

#define NITEMS 4800               // 600 masks x 8 eighths
#define NBLK   2048               // mask grid: full residency

typedef float floatx4 __attribute__((ext_vector_type(4)));

// ---- d_ws byte offsets ----
#define WS_KEYS   0               // u32 [2][81900]  (655200 B, pad to 655360)
#define WS_PART   655360          // u32 [2][16][4096] (524288 B)
#define WS_SEL    1179648         // int [600]

// ---------------- K1: keys + per-block histogram partials ----------------
__global__ __launch_bounds__(256) void hist_kernel(
    const float* __restrict__ logits, uint8_t* __restrict__ ws)
{
    __shared__ uint32_t hist[NBUCKET];
    const int blk   = blockIdx.x;          // 0..31
    const int b     = blk >> 4;
    const int chunk = blk & 15;

    uint32_t* keys = (uint32_t*)(ws + WS_KEYS) + (size_t)b * NQC;
    uint32_t* part = (uint32_t*)(ws + WS_PART) + (size_t)blk * NBUCKET;

    for (int i = threadIdx.x; i < NBUCKET; i += 256) hist[i] = 0u;
    __syncthreads();

    const int base = chunk * CHUNK;
    int end = base + CHUNK; if (end > NQC) end = NQC;
    const float* lg = logits + (size_t)b * NQC;

    for (int i = base + threadIdx.x; i < end; i += 256) {
        float x = lg[i];
        float p = 1.0f / (1.0f + expf(-x));      // identical expression
        uint32_t key = __float_as_uint(p);
        keys[i] = key;
        atomicAdd(&hist[key >> 18], 1u);
    }
    __syncthreads();

    for (int i = threadIdx.x; i < NBUCKET; i += 256) part[i] = hist[i];
}

// -------- K2: reduce+scan (registers) + collect + rank-select + epilogue ----
__global__ __launch_bounds__(1024) void select_kernel(
    const float* __restrict__ boxes_in,  // [B,Q,4]
    const float* __restrict__ logvars,   // [B,Q,4]
    const int*   __restrict__ tsizes,    // [B,2]
    float* __restrict__ out,
    uint8_t* __restrict__ ws)
{
    __shared__ unsigned long long cand[CAND_CAP];
    __shared__ uint32_t wsum[16];
    __shared__ int s_count;
    __shared__ int s_cut;

    const int b    = blockIdx.x;
    const int tid  = threadIdx.x;
    const int lane = tid & 63;
    const int wid  = tid >> 6;

    if (tid == 0) s_count = 0;

    // Reduce 16 partial histograms; each thread owns buckets 4tid..4tid+3.
    const uint32_t* part = (const uint32_t*)(ws + WS_PART)
                         + (size_t)b * NCHUNK * NBUCKET;
    uint4 h = make_uint4(0u, 0u, 0u, 0u);
    #pragma unroll
    for (int p = 0; p < NCHUNK; ++p) {
        uint4 v = *(const uint4*)(part + (size_t)p * NBUCKET + 4 * tid);
        h.x += v.x; h.y += v.y; h.z += v.z; h.w += v.w;
    }
    const uint32_t val = h.x + h.y + h.z + h.w;

    // Wave-level reverse inclusive scan (suffix within wave).
    uint32_t acc = val;
    #pragma unroll
    for (int off = 1; off < 64; off <<= 1) {
        uint32_t o = __shfl_down(acc, off, 64);
        if (lane + off < 64) acc += o;
    }
    if (lane == 0) wsum[wid] = acc;      // wave total (suffix at lane 0)
    __syncthreads();

    uint32_t later = 0;
    for (int w = wid + 1; w < 16; ++w) later += wsum[w];
    const uint32_t sfx      = acc + later;   // sum over threads >= tid
    const uint32_t sfx_next = sfx - val;

    if (sfx >= NSEL && sfx_next < NSEL) {
        // crossing thread: refine to bucket granularity (registers only)
        int a = (int)sfx_next;
        int cut = 4 * tid;
        const uint32_t hh[4] = { h.x, h.y, h.z, h.w };
        for (int k = 3; k >= 0; --k) {
            a += (int)hh[k];
            if (a >= NSEL) { cut = 4 * tid + k; break; }
        }
        s_cut = cut;
    }
    __syncthreads();
    const uint32_t cut = (uint32_t)s_cut;

    // Collect candidates >= cut into LDS.
    const uint32_t* keys = (const uint32_t*)(ws + WS_KEYS) + (size_t)b * NQC;
    for (int i = tid; i < NQC; i += 1024) {
        uint32_t key = keys[i];
        if ((key >> 18) >= cut) {
            int pos = atomicAdd(&s_count, 1);
            if (pos < CAND_CAP) {
                cand[pos] = ((unsigned long long)key << 32)
                          | (uint32_t)(~(uint32_t)i);
            }
        }
    }
    __syncthreads();

    int count = s_count;
    if (count > CAND_CAP) count = CAND_CAP;

    float* out_scores = out;                 // [B*NSEL]
    float* out_labels = out + 600;
    float* out_boxes  = out + 1200;
    float* out_unc    = out + 3600;
    int*   sel        = (int*)(ws + WS_SEL);

    // Rank-select: rank = #candidates with larger composite key.
    // Unique keys => ranks are a permutation; rank<NSEL writes slot directly.
    // Matches descending sort with lower-index-first ties (low word = ~index).
    for (int i = tid; i < count; i += 1024) {
        const unsigned long long my = cand[i];
        int r = 0;
        for (int j = 0; j < count; ++j) r += (cand[j] > my) ? 1 : 0;
        if (r < NSEL) {
            const uint32_t key = (uint32_t)(my >> 32);
            const uint32_t idx = ~((uint32_t)(my & 0xFFFFFFFFull));
            const int q = (int)(idx / CC);
            const int label = (int)(idx - (uint32_t)q * CC);
            const int o = b * NSEL + r;

            out_scores[o] = __uint_as_float(key);
            out_labels[o] = (float)label;

            const float* bx = boxes_in + ((size_t)(b * QQ + q)) * 4;
            float cx = bx[0], cy = bx[1], w = bx[2], hgt = bx[3];
            float hh2 = (float)tsizes[b * 2 + 0];
            float ww2 = (float)tsizes[b * 2 + 1];
            out_boxes[o * 4 + 0] = (cx - 0.5f * w) * ww2;
            out_boxes[o * 4 + 1] = (cy - 0.5f * hgt) * hh2;
            out_boxes[o * 4 + 2] = (cx + 0.5f * w) * ww2;
            out_boxes[o * 4 + 3] = (cy + 0.5f * hgt) * hh2;

            const float* gv = logvars + ((size_t)(b * QQ + q)) * 4;
            float s0 = gv[0] + gv[1];
            float s1 = s0 + gv[2];
            float s2 = s1 + gv[3];
            out_unc[o] = s2 * 0.25f;

            sel[o] = q;
        }
    }
}

// ---------------- K3: bilinear upsample 128->512 + threshold ----------
// R10 per-item code, grid 1600->2048 blocks (full 2048-block residency,
// 32 waves/CU) with exact prefix partition: block i owns items
// [i*4800/2048, (i+1)*4800/2048)  (2 or 3 items).
__global__ __launch_bounds__(256) void mask_kernel(
    const float* __restrict__ masks_in,  // [B,Q,128,128]
    const int*   __restrict__ sel,       // [B*NSEL]
    float* __restrict__ out_masks)       // [B*NSEL,512,512]
{
    __shared__ float S[18 * MW];         // 9216 B

    const int xg = threadIdx.x & 127;    // output cols 4xg..4xg+3
    const int rh = threadIdx.x >> 7;     // row half (0/1) within 64-row item
    const int cm1 = (xg == 0)   ? 0   : xg - 1;
    const int cp1 = (xg == 127) ? 127 : xg + 1;
    const bool eL = (xg == 0);
    const bool eR = (xg == 127);

    const int it0 = (int)(((long long)blockIdx.x * NITEMS) / NBLK);
    const int it1 = (int)(((long long)(blockIdx.x + 1) * NITEMS) / NBLK);

    for (int item = it0; item < it1; ++item) {
        const int m = item >> 3;         // 0..599
        const int e = item & 7;          // eighth: 64 rows
        const int b = m / NSEL;
        const int q = sel[m];

        const float* src = masks_in + ((size_t)(b * QQ + q)) * (MH * MW);
        float* dst = out_masks + (size_t)m * (TGT * TGT);

        const int y0   = e * 64;
        const int r_lo = (e == 0) ? 0   : (16 * e - 1);
        const int r_hi = (e == 7) ? 127 : (16 * e + 16);
        const int nrows = r_hi - r_lo + 1;   // 17 or 18

        {
            const float4* s4 = (const float4*)(src + (size_t)r_lo * MW);
            float4* d4 = (float4*)S;
            const int n4 = nrows * (MW / 4);
            for (int i = threadIdx.x; i < n4; i += 256) d4[i] = s4[i];
        }
        __syncthreads();

        // ---- Phase 1: horizontal blends for input rows k0-1 .. k0+8 ----
        const int k0    = 16 * e + 8 * rh;   // first out-row group index
        const int rbase = k0 - 1;
        floatx4 h[10];
        #pragma unroll
        for (int j = 0; j < 10; ++j) {
            int r = rbase + j;
            r = (r < 0) ? 0 : (r > MH - 1 ? MH - 1 : r);
            const float* R = S + (r - r_lo) * MW;
            const float a = R[cm1];
            const float c = R[xg];
            const float p = R[cp1];
            floatx4 v;
            v.x = eL ? c : fmaf(0.375f, a, 0.625f * c);
            v.y = eL ? c : fmaf(0.125f, a, 0.875f * c);
            v.z = eR ? c : fmaf(0.125f, p, 0.875f * c);
            v.w = eR ? c : fmaf(0.375f, p, 0.625f * c);
            h[j] = v;
        }

        // ---- Phase 2: vertical lerps + burst stores ----
        float* dhalf = dst + (size_t)(y0 + rh * 32) * TGT + 4 * xg;
        #pragma unroll
        for (int g = 0; g < 8; ++g) {
            const floatx4 hA = h[g];
            const floatx4 hB = h[g + 1];
            const floatx4 hC = h[g + 2];
            const floatx4 dAB = hB - hA;
            const floatx4 dBC = hC - hB;

            floatx4 vA, vB, vC, vD;
            #pragma unroll
            for (int u = 0; u < 4; ++u) {
                vA[u] = fmaf(0.625f, dAB[u], hA[u]);
                vB[u] = fmaf(0.875f, dAB[u], hA[u]);
                vC[u] = fmaf(0.125f, dBC[u], hB[u]);
                vD[u] = fmaf(0.375f, dBC[u], hB[u]);
            }
            floatx4 rA, rB, rC, rD;
            #pragma unroll
            for (int u = 0; u < 4; ++u) {
                rA[u] = (vA[u] > 0.0f) ? 1.0f : 0.0f;
                rB[u] = (vB[u] > 0.0f) ? 1.0f : 0.0f;
                rC[u] = (vC[u] > 0.0f) ? 1.0f : 0.0f;
                rD[u] = (vD[u] > 0.0f) ? 1.0f : 0.0f;
            }
            floatx4* p0 = (floatx4*)(dhalf + (size_t)(4 * g    ) * TGT);
            floatx4* p1 = (floatx4*)(dhalf + (size_t)(4 * g + 1) * TGT);
            floatx4* p2 = (floatx4*)(dhalf + (size_t)(4 * g + 2) * TGT);
            floatx4* p3 = (floatx4*)(dhalf + (size_t)(4 * g + 3) * TGT);
            __builtin_nontemporal_store(rA, p0);
            __builtin_nontemporal_store(rB, p1);
            __builtin_nontemporal_store(rC, p2);
            __builtin_nontemporal_store(rD, p3);
        }
        __syncthreads();   // LDS reuse guard before next item's stage
    }
}

extern "C" void kernel_launch(void* const* d_in, const int* in_sizes, int n_in,
                              void* d_out, int out_size, void* d_ws, size_t ws_size,
                              hipStream_t stream) {
    (void)in_sizes; (void)n_in; (void)out_size; (void)ws_size;

    const float* pred_logits  = (const float*)d_in[0];  // [2,900,91]
    const float* pred_boxes   = (const float*)d_in[1];  // [2,900,4]
    const float* pred_masks   = (const float*)d_in[2];  // [2,900,128,128]
    const float* pred_logvars = (const float*)d_in[3];  // [2,900,4]
    const int*   target_sizes = (const int*)d_in[4];    // [2,2]

    float*   out = (float*)d_out;
    uint8_t* ws  = (uint8_t*)d_ws;

    hipLaunchKernelGGL(hist_kernel, dim3(BB * NCHUNK), dim3(256), 0, stream,
                       pred_logits, ws);
    hipLaunchKernelGGL(select_kernel, dim3(BB), dim3(1024), 0, stream,
                       pred_boxes, pred_logvars, target_sizes, out, ws);

    float* out_masks = out + 4200;
    const int* sel = (const int*)(ws + WS_SEL);
    hipLaunchKernelGGL(mask_kernel, dim3(NBLK), dim3(256), 0, stream,
                       pred_masks, sel, out_masks);
}